// Round 12
// baseline (331.721 us; speedup 1.0000x reference)
//
#include <hip/hip_runtime.h>
#include <hip/hip_bf16.h>

typedef __bf16 bf16x8 __attribute__((ext_vector_type(8)));
typedef float floatx4 __attribute__((ext_vector_type(4)));

constexpr int Dm = 1024;
constexpr int Hh = 16;
constexpr int HD = 64;
constexpr int FF = 4096;
constexpr int Tt = 2048;
constexpr int Bb = 2;
constexpr int MR = Bb * Tt;  // 4096 rows

typedef const __attribute__((address_space(1))) void* gas1p;
typedef __attribute__((address_space(3))) void* las3p;

// ------ fused prep: 6 weight transposes + LN1, one launch ------
// blocks [0,12288): 32x32 transpose tiles (as before).
// blocks [12288,16384): LN row (id-12288) of x -> h1.
__global__ __launch_bounds__(256) void prep_kernel(
    const float* __restrict__ wq, const float* __restrict__ wk,
    const float* __restrict__ wv, const float* __restrict__ wo,
    const float* __restrict__ w1, const float* __restrict__ w2,
    __hip_bfloat16* __restrict__ WqkvT, __hip_bfloat16* __restrict__ WoT,
    __hip_bfloat16* __restrict__ W1T, __hip_bfloat16* __restrict__ W2T,
    const float* __restrict__ x, const float* __restrict__ alpha,
    const float* __restrict__ shift, __hip_bfloat16* __restrict__ h1) {
  int id = blockIdx.x;
  int tid = threadIdx.x;
  if (id < 12288) {
    __shared__ float tile[32][33];
    const float* W;
    __hip_bfloat16* WT;
    int l, sh, K, N;
    if (id < 4096) {
      int m = id >> 10;
      l = id & 1023; sh = 5; K = Dm; N = Dm;
      W = (m == 0) ? wq : (m == 1) ? wk : (m == 2) ? wv : wo;
      WT = (m == 0) ? WqkvT
                    : (m == 1) ? (WqkvT + (size_t)Dm * Dm)
                               : (m == 2) ? (WqkvT + 2 * (size_t)Dm * Dm) : WoT;
    } else if (id < 8192) {
      l = id - 4096; sh = 7; K = Dm; N = FF; W = w1; WT = W1T;
    } else {
      l = id - 8192; sh = 5; K = FF; N = Dm; W = w2; WT = W2T;
    }
    int n0 = (l & ((1 << sh) - 1)) * 32;
    int k0 = (l >> sh) * 32;
    int tx = tid & 31, ty = tid >> 5;
#pragma unroll
    for (int i = 0; i < 4; ++i) {
      int k = k0 + ty + i * 8;
      tile[ty + i * 8][tx] = W[(size_t)k * N + n0 + tx];
    }
    __syncthreads();
    int r = tid >> 3;
    int cq = (tid & 7) * 4;
    __hip_bfloat16 ov[4];
#pragma unroll
    for (int j = 0; j < 4; ++j) ov[j] = __float2bfloat16(tile[cq + j][r]);
    *reinterpret_cast<uint2*>(&WT[(size_t)(n0 + r) * K + k0 + cq]) =
        *reinterpret_cast<const uint2*>(ov);
  } else {
    // LN row
    int row = id - 12288;
    const float4 v = ((const float4*)(x + (size_t)row * Dm))[tid];
    float s = v.x + v.y + v.z + v.w;
    float ss = v.x * v.x + v.y * v.y + v.z * v.z + v.w * v.w;
#pragma unroll
    for (int o = 32; o; o >>= 1) {
      s += __shfl_down(s, o);
      ss += __shfl_down(ss, o);
    }
    __shared__ float rs[4], rss[4];
    int w = tid >> 6, lane = tid & 63;
    if (lane == 0) { rs[w] = s; rss[w] = ss; }
    __syncthreads();
    float tot = rs[0] + rs[1] + rs[2] + rs[3];
    float tots = rss[0] + rss[1] + rss[2] + rss[3];
    float mean = tot * (1.f / Dm);
    float var = tots * (1.f / Dm) - mean * mean;
    float rstd = rsqrtf(var + 1e-5f);
    float4 al = ((const float4*)alpha)[tid];
    float4 sf = ((const float4*)shift)[tid];
    __hip_bfloat16 ov[4];
    ov[0] = __float2bfloat16((v.x - mean) * rstd * al.x + sf.x);
    ov[1] = __float2bfloat16((v.y - mean) * rstd * al.y + sf.y);
    ov[2] = __float2bfloat16((v.z - mean) * rstd * al.z + sf.z);
    ov[3] = __float2bfloat16((v.w - mean) * rstd * al.w + sf.w);
    *reinterpret_cast<uint2*>(h1 + (size_t)row * Dm + tid * 4) =
        *reinterpret_cast<const uint2*>(ov);
  }
}

// ---------------- LayerNorm (fp32 in, bf16 out) ----------------
__global__ __launch_bounds__(256) void ln_bf16_kernel(
    const float* __restrict__ x, const float* __restrict__ alpha,
    const float* __restrict__ shift, __hip_bfloat16* __restrict__ out) {
  int row = blockIdx.x;
  const float4 v = ((const float4*)(x + (size_t)row * Dm))[threadIdx.x];
  float s = v.x + v.y + v.z + v.w;
  float ss = v.x * v.x + v.y * v.y + v.z * v.z + v.w * v.w;
#pragma unroll
  for (int o = 32; o; o >>= 1) {
    s += __shfl_down(s, o);
    ss += __shfl_down(ss, o);
  }
  __shared__ float rs[4], rss[4];
  int w = threadIdx.x >> 6, lane = threadIdx.x & 63;
  if (lane == 0) { rs[w] = s; rss[w] = ss; }
  __syncthreads();
  float tot = rs[0] + rs[1] + rs[2] + rs[3];
  float tots = rss[0] + rss[1] + rss[2] + rss[3];
  float mean = tot * (1.f / Dm);
  float var = tots * (1.f / Dm) - mean * mean;
  float rstd = rsqrtf(var + 1e-5f);
  float4 al = ((const float4*)alpha)[threadIdx.x];
  float4 sf = ((const float4*)shift)[threadIdx.x];
  __hip_bfloat16 ov[4];
  ov[0] = __float2bfloat16((v.x - mean) * rstd * al.x + sf.x);
  ov[1] = __float2bfloat16((v.y - mean) * rstd * al.y + sf.y);
  ov[2] = __float2bfloat16((v.z - mean) * rstd * al.z + sf.z);
  ov[3] = __float2bfloat16((v.w - mean) * rstd * al.w + sf.w);
  *reinterpret_cast<uint2*>(out + (size_t)row * Dm + threadIdx.x * 4) =
      *reinterpret_cast<const uint2*>(ov);
}

// ============ 256x256 GEMM, 4-phase K-tile, 2 barriers/tile ================
// ROUND-9 PROVEN SCHEDULE (2-barrier free-slip; pacing barriers regressed).
// EPI 2: +bias, GELU, bf16. EPI 3: fused QKV scatter; V third written
//        DIRECTLY transposed into vtb (P3 param) -> vtrans kernel deleted.
// EPI 4: split-K fp32 partial (z<3 -> Cout + z*M*N, z==3 -> P3).
// Grid (8, nwg/8, S): bx = XCD owns a contiguous m-band of tiles.
template <int EPI>
__global__ __launch_bounds__(512, 2) void gemm256(
    const __bf16* __restrict__ A, const __bf16* __restrict__ BT,
    void* __restrict__ Cout, const float* __restrict__ bias,
    float* __restrict__ P3, int M, int N, int K, int Ks) {
  __shared__ __bf16 As[2][2][256 * 32];
  __shared__ __bf16 Bs[2][2][256 * 32];
  const int tid = threadIdx.x;
  const int w = tid >> 6, lane = tid & 63;
  const int r16 = lane & 15, quad = lane >> 4;
  const int wm = w >> 2, wn = w & 3;  // 2 x 4 wave grid
  const int ntn = N >> 8;
  const int T = blockIdx.x * gridDim.y + blockIdx.y;
  const int tm = T / ntn, tn = T - tm * ntn;
  const int m0 = tm * 256, n0 = tn * 256;
  const int k_off = blockIdx.z * Ks;
  int kcols = K - k_off;
  if (kcols > Ks) kcols = Ks;
  const int nt = kcols >> 6;  // K-tiles of 64 (>= 2 at all call sites)
  const __bf16* Ap = A + k_off;
  const __bf16* Bp = BT + k_off;

  auto stageA = [&](int t, int pl, int buf) {
#pragma unroll
    for (int q = 0; q < 2; ++q) {
      int idx = tid + q * 512;
      int row = idx >> 2;
      int gcb = (idx & 3) ^ ((row >> 1) & 3);
      __builtin_amdgcn_global_load_lds(
          (gas1p)(Ap + (size_t)(m0 + row) * K + t * 64 + pl * 32 + gcb * 8),
          (las3p)(&As[buf][pl][idx * 8]), 16, 0, 0);
    }
  };
  auto stageB = [&](int t, int pl, int buf) {
#pragma unroll
    for (int q = 0; q < 2; ++q) {
      int idx = tid + q * 512;
      int row = idx >> 2;
      int gcb = (idx & 3) ^ ((row >> 1) & 3);
      __builtin_amdgcn_global_load_lds(
          (gas1p)(Bp + (size_t)(n0 + row) * K + t * 64 + pl * 32 + gcb * 8),
          (las3p)(&Bs[buf][pl][idx * 8]), 16, 0, 0);
    }
  };

  int aoffL[8], boffL[4];
#pragma unroll
  for (int i = 0; i < 8; ++i) {
    int ra = wm * 128 + i * 16 + r16;
    aoffL[i] = ra * 32 + (quad ^ ((ra >> 1) & 3)) * 8;
  }
#pragma unroll
  for (int i = 0; i < 4; ++i) {
    int rb = wn * 64 + i * 16 + r16;
    boffL[i] = rb * 32 + (quad ^ ((rb >> 1) & 3)) * 8;
  }

#define LDA(pl_, i_) *reinterpret_cast<const bf16x8*>(&As[c][pl_][aoffL[i_]])
#define LDB(pl_, i_) *reinterpret_cast<const bf16x8*>(&Bs[c][pl_][boffL[i_]])
#define MFMA4(acc_, a_)                                                        \
  acc_[0] = __builtin_amdgcn_mfma_f32_16x16x32_bf16(a_, b0, acc_[0], 0, 0, 0); \
  acc_[1] = __builtin_amdgcn_mfma_f32_16x16x32_bf16(a_, b1, acc_[1], 0, 0, 0); \
  acc_[2] = __builtin_amdgcn_mfma_f32_16x16x32_bf16(a_, b2, acc_[2], 0, 0, 0); \
  acc_[3] = __builtin_amdgcn_mfma_f32_16x16x32_bf16(a_, b3, acc_[3], 0, 0, 0);

  floatx4 acc[8][4] = {};
  // prologue: full tile 0, order Apl0,Bpl0,Apl1,Bpl1 -> oldest 4 = pl0 pair
  stageA(0, 0, 0);
  stageB(0, 0, 0);
  stageA(0, 1, 0);
  stageB(0, 1, 0);
  asm volatile("s_waitcnt vmcnt(4)\n\ts_barrier" ::: "memory");

  for (int t = 0; t < nt; ++t) {
    const int c = t & 1, nc = c ^ 1;
    const bool pre = (t + 1 < nt);
    bf16x8 a0, a1, a2, a3, b0, b1, b2, b3;
    // ---- phase 0: pl0, mi0-3 (no barrier) ----
    b0 = LDB(0, 0); b1 = LDB(0, 1); b2 = LDB(0, 2); b3 = LDB(0, 3);
    a0 = LDA(0, 0); a1 = LDA(0, 1); a2 = LDA(0, 2); a3 = LDA(0, 3);
    if (pre) stageA(t + 1, 0, nc);
    __builtin_amdgcn_s_setprio(1);
    MFMA4(acc[0], a0); MFMA4(acc[1], a1); MFMA4(acc[2], a2); MFMA4(acc[3], a3);
    __builtin_amdgcn_s_setprio(0);
    // ---- phase 1: pl0, mi4-7 ----
    a0 = LDA(0, 4); a1 = LDA(0, 5); a2 = LDA(0, 6); a3 = LDA(0, 7);
    if (pre) stageB(t + 1, 0, nc);
    __builtin_amdgcn_s_setprio(1);
    MFMA4(acc[4], a0); MFMA4(acc[5], a1); MFMA4(acc[6], a2); MFMA4(acc[7], a3);
    __builtin_amdgcn_s_setprio(0);
    if (pre)
      asm volatile("s_waitcnt vmcnt(4)\n\ts_barrier" ::: "memory");
    else
      asm volatile("s_waitcnt vmcnt(0)\n\ts_barrier" ::: "memory");
    // ---- phase 2: pl1, mi0-3 (no barrier) ----
    b0 = LDB(1, 0); b1 = LDB(1, 1); b2 = LDB(1, 2); b3 = LDB(1, 3);
    a0 = LDA(1, 0); a1 = LDA(1, 1); a2 = LDA(1, 2); a3 = LDA(1, 3);
    if (pre) stageA(t + 1, 1, nc);
    __builtin_amdgcn_s_setprio(1);
    MFMA4(acc[0], a0); MFMA4(acc[1], a1); MFMA4(acc[2], a2); MFMA4(acc[3], a3);
    __builtin_amdgcn_s_setprio(0);
    // ---- phase 3: pl1, mi4-7 ----
    a0 = LDA(1, 4); a1 = LDA(1, 5); a2 = LDA(1, 6); a3 = LDA(1, 7);
    if (pre) stageB(t + 1, 1, nc);
    __builtin_amdgcn_s_setprio(1);
    MFMA4(acc[4], a0); MFMA4(acc[5], a1); MFMA4(acc[6], a2); MFMA4(acc[7], a3);
    __builtin_amdgcn_s_setprio(0);
    if (pre)
      asm volatile("s_waitcnt vmcnt(4)\n\ts_barrier" ::: "memory");
    else
      asm volatile("s_waitcnt vmcnt(0)\n\ts_barrier" ::: "memory");
  }
#undef LDA
#undef LDB
#undef MFMA4

  if (EPI == 3) {
    // fused QKV scatter; V third (qkv==2) written transposed into vtb (=P3)
    __hip_bfloat16* qk = (__hip_bfloat16*)Cout;
    __hip_bfloat16* vtb = (__hip_bfloat16*)P3;
#pragma unroll
    for (int mi = 0; mi < 8; ++mi)
#pragma unroll
      for (int ni = 0; ni < 4; ++ni) {
        int row0 = m0 + wm * 128 + mi * 16 + quad * 4;
        int col = n0 + wn * 64 + ni * 16 + r16;
        int qkv = col >> 10, rem = col & 1023;
        int h = rem >> 6, d = rem & 63;
        int bb = row0 >> 11, t0 = row0 & 2047;  // 4 rows share bb (4 | 2048)
        if (qkv < 2) {
#pragma unroll
          for (int r = 0; r < 4; ++r)
            qk[(size_t)qkv * (MR * Dm) +
               ((size_t)(bb * Hh + h) * Tt + t0 + r) * HD + d] =
                __float2bfloat16(acc[mi][ni][r]);
        } else {
          __hip_bfloat16 ov[4];
#pragma unroll
          for (int r = 0; r < 4; ++r) ov[r] = __float2bfloat16(acc[mi][ni][r]);
          *reinterpret_cast<uint2*>(
              &vtb[((size_t)(bb * Hh + h) * HD + d) * Tt + t0]) =
              *reinterpret_cast<const uint2*>(ov);
        }
      }
    return;
  }

  float* dst4 = nullptr;
  if (EPI == 4)
    dst4 = (blockIdx.z == 3) ? P3
                             : (float*)Cout + (size_t)blockIdx.z * ((size_t)M * N);
#pragma unroll
  for (int mi = 0; mi < 8; ++mi)
#pragma unroll
    for (int ni = 0; ni < 4; ++ni)
#pragma unroll
      for (int r = 0; r < 4; ++r) {
        int row = m0 + wm * 128 + mi * 16 + quad * 4 + r;
        int col = n0 + wn * 64 + ni * 16 + r16;
        float vacc = acc[mi][ni][r];
        if (EPI == 2) {
          vacc += bias[col];
          float u = vacc + 0.044715f * vacc * vacc * vacc;
          float e = __builtin_amdgcn_exp2f(2.3025851f * u);
          float th = 1.f - 2.f * __builtin_amdgcn_rcpf(e + 1.f);
          ((__hip_bfloat16*)Cout)[(size_t)row * N + col] =
              __float2bfloat16(0.5f * vacc * (1.f + th));
        } else {  // EPI 4: split-K raw partial, fp32
          dst4[(size_t)row * N + col] = vacc;
        }
      }
}

// ---- split-K=4 reduce: out = P0+P1+P2+P3 + bias + out (out holds x2) ----
__global__ __launch_bounds__(256) void reduce4_kernel(
    const float* __restrict__ P, const float* __restrict__ P3,
    const float* __restrict__ bias, float* __restrict__ out) {
  size_t idx = (size_t)blockIdx.x * 256 + threadIdx.x;  // float4 index
  const size_t MN4 = (size_t)MR * Dm / 4;
  float4 p0 = ((const float4*)P)[idx];
  float4 p1 = ((const float4*)P)[MN4 + idx];
  float4 p2 = ((const float4*)P)[2 * MN4 + idx];
  float4 p3 = ((const float4*)P3)[idx];
  float4 b = ((const float4*)bias)[idx & (Dm / 4 - 1)];
  float4 o = ((float4*)out)[idx];
  o.x += p0.x + p1.x + p2.x + p3.x + b.x;
  o.y += p0.y + p1.y + p2.y + p3.y + b.y;
  o.z += p0.z + p1.z + p2.z + p3.z + b.z;
  o.w += p0.w + p1.w + p2.w + p3.w + b.w;
  ((float4*)out)[idx] = o;
}

// ============ 128x128 GEMM, 4-phase thinned schedule (wo ONLY) =============
// Proven ~8.5us faster than gemm_tiled64 for wo (K=1024). Measured 77us on
// w2 (K=4096) -- do NOT use for the fat GEMMs (per-phase density too low).
__global__ __launch_bounds__(512, 4) void gemm128(
    const __bf16* __restrict__ A, const __bf16* __restrict__ BT,
    float* __restrict__ Cout, const float* __restrict__ bias,
    const float* __restrict__ resid, int M, int N, int K) {
  __shared__ __bf16 As[2][2][128 * 32];
  __shared__ __bf16 Bs[2][2][128 * 32];
  const int tid = threadIdx.x;
  const int w = tid >> 6, lane = tid & 63;
  const int r16 = lane & 15, quad = lane >> 4;
  const int wm = w >> 2, wn = w & 3;  // 2 x 4 wave grid
  const int ntn = N >> 7;
  const int T = blockIdx.x * gridDim.y + blockIdx.y;
  const int tm = T / ntn, tn = T - tm * ntn;
  const int m0 = tm * 128, n0 = tn * 128;
  const int nt = K >> 6;

  const int s_row = tid >> 2;
  const int s_gcb = (tid & 3) ^ ((s_row >> 1) & 3);
  auto stageA = [&](int t, int pl, int buf) {
    __builtin_amdgcn_global_load_lds(
        (gas1p)(A + (size_t)(m0 + s_row) * K + t * 64 + pl * 32 + s_gcb * 8),
        (las3p)(&As[buf][pl][tid * 8]), 16, 0, 0);
  };
  auto stageB = [&](int t, int pl, int buf) {
    __builtin_amdgcn_global_load_lds(
        (gas1p)(BT + (size_t)(n0 + s_row) * K + t * 64 + pl * 32 + s_gcb * 8),
        (las3p)(&Bs[buf][pl][tid * 8]), 16, 0, 0);
  };

  int aoffL[4], boffL[2];
#pragma unroll
  for (int i = 0; i < 4; ++i) {
    int ra = wm * 64 + i * 16 + r16;
    aoffL[i] = ra * 32 + (quad ^ ((ra >> 1) & 3)) * 8;
  }
#pragma unroll
  for (int i = 0; i < 2; ++i) {
    int rb = wn * 32 + i * 16 + r16;
    boffL[i] = rb * 32 + (quad ^ ((rb >> 1) & 3)) * 8;
  }

#define LDA(pl_, i_) *reinterpret_cast<const bf16x8*>(&As[c][pl_][aoffL[i_]])
#define LDB(pl_, i_) *reinterpret_cast<const bf16x8*>(&Bs[c][pl_][boffL[i_]])
#define MFMA2(acc_, a_)                                                        \
  acc_[0] = __builtin_amdgcn_mfma_f32_16x16x32_bf16(a_, b0, acc_[0], 0, 0, 0); \
  acc_[1] = __builtin_amdgcn_mfma_f32_16x16x32_bf16(a_, b1, acc_[1], 0, 0, 0);

  floatx4 acc[4][2] = {};
  stageA(0, 0, 0);
  stageB(0, 0, 0);
  stageA(0, 1, 0);
  stageB(0, 1, 0);
  asm volatile("s_waitcnt vmcnt(2)\n\ts_barrier" ::: "memory");

  for (int t = 0; t < nt; ++t) {
    const int c = t & 1, nc = c ^ 1;
    const bool pre = (t + 1 < nt);
    bf16x8 a0, a1, b0, b1;
    b0 = LDB(0, 0); b1 = LDB(0, 1);
    a0 = LDA(0, 0); a1 = LDA(0, 1);
    if (pre) stageA(t + 1, 0, nc);
    __builtin_amdgcn_s_setprio(1);
    MFMA2(acc[0], a0); MFMA2(acc[1], a1);
    __builtin_amdgcn_s_setprio(0);
    a0 = LDA(0, 2); a1 = LDA(0, 3);
    if (pre) stageB(t + 1, 0, nc);
    __builtin_amdgcn_s_setprio(1);
    MFMA2(acc[2], a0); MFMA2(acc[3], a1);
    __builtin_amdgcn_s_setprio(0);
    if (pre)
      asm volatile("s_waitcnt vmcnt(2)\n\ts_barrier" ::: "memory");
    else
      asm volatile("s_waitcnt vmcnt(0)\n\ts_barrier" ::: "memory");
    b0 = LDB(1, 0); b1 = LDB(1, 1);
    a0 = LDA(1, 0); a1 = LDA(1, 1);
    if (pre) stageA(t + 1, 1, nc);
    __builtin_amdgcn_s_setprio(1);
    MFMA2(acc[0], a0); MFMA2(acc[1], a1);
    __builtin_amdgcn_s_setprio(0);
    a0 = LDA(1, 2); a1 = LDA(1, 3);
    if (pre) stageB(t + 1, 1, nc);
    __builtin_amdgcn_s_setprio(1);
    MFMA2(acc[2], a0); MFMA2(acc[3], a1);
    __builtin_amdgcn_s_setprio(0);
    if (pre)
      asm volatile("s_waitcnt vmcnt(2)\n\ts_barrier" ::: "memory");
    else
      asm volatile("s_waitcnt vmcnt(0)\n\ts_barrier" ::: "memory");
  }
#undef LDA
#undef LDB
#undef MFMA2

#pragma unroll
  for (int mi = 0; mi < 4; ++mi)
#pragma unroll
    for (int ni = 0; ni < 2; ++ni)
#pragma unroll
      for (int r = 0; r < 4; ++r) {
        int row = m0 + wm * 64 + mi * 16 + quad * 4 + r;
        int col = n0 + wn * 32 + ni * 16 + r16;
        float vacc = acc[mi][ni][r] + bias[col] + resid[(size_t)row * N + col];
        Cout[(size_t)row * N + col] = vacc;
      }
}

// ---------------- MFMA flash attention, fixed-max softmax ----------------
__global__ __launch_bounds__(256) void attn_kernel(
    const __bf16* __restrict__ qp, const __bf16* __restrict__ kp,
    const __bf16* __restrict__ vtp, __bf16* __restrict__ ctx) {
  __shared__ __bf16 Ks[2][64 * 64];   // [kcol][d], swizzled chunks
  __shared__ __bf16 Vt[2][80 * 64];   // [d][kcol]; rows 64..79: ones/zeros
  __shared__ __bf16 Ps[4 * 16 * 72];  // per-wave P [qrow][kcol]
  int bh = blockIdx.x;
  int b = bh >> 4, h = bh & 15;
  int qt = 31 - blockIdx.y;  // longest blocks first
  int tid = threadIdx.x;
  int w = tid >> 6, lane = tid & 63;
  int r16 = lane & 15, quad = lane >> 4;
  int q0 = qt * 64;
  const size_t base = (size_t)bh * Tt * HD;

  {
    int r = 64 + (tid >> 4);
    int c = (tid & 15) * 4;
    __bf16 val = (r == 64) ? (__bf16)1.0f : (__bf16)0.0f;
#pragma unroll
    for (int bu = 0; bu < 2; ++bu) {
      __bf16* p = &Vt[bu][r * 64 + c];
      p[0] = val; p[1] = val; p[2] = val; p[3] = val;
    }
  }

  const float QS = 0.125f * 1.44269504088896f;
  bf16x8 aq[2];
#pragma unroll
  for (int ks = 0; ks < 2; ++ks) {
    bf16x8 t = *reinterpret_cast<const bf16x8*>(
        qp + base + (size_t)(q0 + w * 16 + r16) * HD + ks * 32 + quad * 8);
#pragma unroll
    for (int j = 0; j < 8; ++j) t[j] = (__bf16)((float)t[j] * QS);
    aq[ks] = t;
  }

  auto stage = [&](int kt, int buf) {
#pragma unroll
    for (int p = 0; p < 2; ++p) {
      int idx = tid + p * 256;
      int row = idx >> 3, c = idx & 7;
      int gc = c ^ (row & 7);
      __builtin_amdgcn_global_load_lds(
          (gas1p)(kp + base + (size_t)(kt * 64 + row) * HD + gc * 8),
          (las3p)(&Ks[buf][idx * 8]), 16, 0, 0);
      __builtin_amdgcn_global_load_lds(
          (gas1p)(vtp + base + (size_t)row * Tt + kt * 64 + gc * 8),
          (las3p)(&Vt[buf][idx * 8]), 16, 0, 0);
    }
  };

  floatx4 O[5] = {};
  stage(0, 0);
  for (int kt = 0; kt <= qt; ++kt) {
    int cur = kt & 1;
    __syncthreads();
    if (kt < qt) stage(kt + 1, cur ^ 1);

    floatx4 sacc[4] = {};
#pragma unroll
    for (int ks = 0; ks < 2; ++ks)
#pragma unroll
      for (int ni = 0; ni < 4; ++ni) {
        int row = ni * 16 + r16;
        bf16x8 bk = *reinterpret_cast<const bf16x8*>(
            &Ks[cur][row * 64 + (((ks << 2) | quad) ^ (r16 & 7)) * 8]);
        sacc[ni] = __builtin_amdgcn_mfma_f32_16x16x32_bf16(aq[ks], bk, sacc[ni], 0, 0, 0);
      }

    bool diag = (kt == qt);
#pragma unroll
    for (int ni = 0; ni < 4; ++ni)
#pragma unroll
      for (int r = 0; r < 4; ++r) {
        float sv = sacc[ni][r];
        if (diag)
          sv = (ni * 16 + r16 <= w * 16 + quad * 4 + r) ? sv : -__builtin_inff();
        Ps[w * 1152 + (quad * 4 + r) * 72 + ni * 16 + r16] =
            (__bf16)__builtin_amdgcn_exp2f(sv);
      }

#pragma unroll
    for (int ks = 0; ks < 2; ++ks) {
      bf16x8 ap = *reinterpret_cast<const bf16x8*>(
          &Ps[w * 1152 + r16 * 72 + ks * 32 + quad * 8]);
#pragma unroll
      for (int ni = 0; ni < 5; ++ni) {
        int row = ni * 16 + r16;
        bf16x8 bv = *reinterpret_cast<const bf16x8*>(
            &Vt[cur][row * 64 + (((ks << 2) | quad) ^ (r16 & 7)) * 8]);
        O[ni] = __builtin_amdgcn_mfma_f32_16x16x32_bf16(ap, bv, O[ni], 0, 0, 0);
      }
    }
  }

  float invl[4];
#pragma unroll
  for (int r = 0; r < 4; ++r) {
    float l = __shfl(O[4][r], lane & 48);
    invl[r] = 1.f / l;
  }
#pragma unroll
  for (int r = 0; r < 4; ++r) {
    int qrow = q0 + w * 16 + quad * 4 + r;
    __bf16* op = ctx + ((size_t)(b * Tt + qrow)) * Dm + h * HD;
#pragma unroll
    for (int ni = 0; ni < 4; ++ni)
      op[ni * 16 + r16] = (__bf16)(O[ni][r] * invl[r]);
  }
}

extern "C" void kernel_launch(void* const* d_in, const int* in_sizes, int n_in,
                              void* d_out, int out_size, void* d_ws, size_t ws_size,
                              hipStream_t stream) {
  const float* x = (const float*)d_in[0];
  const float* wq = (const float*)d_in[1];
  const float* wk = (const float*)d_in[2];
  const float* wv = (const float*)d_in[3];
  const float* wo = (const float*)d_in[4];
  const float* bo = (const float*)d_in[5];
  const float* w1 = (const float*)d_in[6];
  const float* b1 = (const float*)d_in[7];
  const float* w2 = (const float*)d_in[8];
  const float* b2 = (const float*)d_in[9];
  const float* a1 = (const float*)d_in[10];
  const float* s1 = (const float*)d_in[11];
  const float* a2 = (const float*)d_in[12];
  const float* s2 = (const float*)d_in[13];
  float* out = (float*)d_out;
  char* ws = (char*)d_ws;

  const size_t MB = 1024 * 1024;
  __hip_bfloat16* WqkvT = (__hip_bfloat16*)(ws + 0 * MB);  // 6MB: WqT|WkT|WvT
  __hip_bfloat16* WoT = (__hip_bfloat16*)(ws + 6 * MB);
  __hip_bfloat16* W1T = (__hip_bfloat16*)(ws + 8 * MB);
  __hip_bfloat16* W2T = (__hip_bfloat16*)(ws + 16 * MB);
  __hip_bfloat16* h1  = (__hip_bfloat16*)(ws + 24 * MB);
  __hip_bfloat16* qkvb = (__hip_bfloat16*)(ws + 32 * MB);  // 16MB used: q|k head-major
  __hip_bfloat16* ctxb = (__hip_bfloat16*)(ws + 56 * MB);  // token-major
  __hip_bfloat16* h2  = (__hip_bfloat16*)(ws + 64 * MB);
  // g (FFN1 out, 32MB) overlays dead qkvb+ctxb at [32,64).
  __hip_bfloat16* g   = (__hip_bfloat16*)(ws + 32 * MB);
  __hip_bfloat16* vtb = (__hip_bfloat16*)(ws + 104 * MB);  // 8MB: V^T [B*H,64,T]
  // split-K=4 fp32 partials: slices 0-2 (48MB) at [64,112) over dead h2/vtb;
  // slice 3 (16MB) at [0,16) over dead WqkvT/WoT/W1T (all consumed by w2 time)
  float* Pbuf = (float*)(ws + 64 * MB);
  float* P3buf = (float*)(ws + 0 * MB);

  // one launch: 6 weight transposes + LN1 (disjoint block ranges)
  prep_kernel<<<12288 + MR, 256, 0, stream>>>(
      wq, wk, wv, wo, w1, w2, WqkvT, WoT, W1T, W2T, x, a1, s1, h1);

  // QKV: M=4096, N=3072 -> 192 tiles, grid (8,24). V third written directly
  // transposed into vtb (P3 param) -> vtrans kernel eliminated.
  gemm256<3><<<dim3(8, 24, 1), 512, 0, stream>>>(
      (const __bf16*)h1, (const __bf16*)WqkvT, qkvb, nullptr, (float*)vtb,
      MR, 3 * Dm, Dm, Dm);

  attn_kernel<<<dim3(Bb * Hh, Tt / 64), 256, 0, stream>>>(
      (const __bf16*)qkvb, (const __bf16*)(qkvb + (size_t)MR * Dm),
      (const __bf16*)vtb, (__bf16*)ctxb);

  // x2 = ctx @ Wo + bo + x  (gemm128: proven ~8.5us faster than tiled64 here)
  gemm128<<<dim3(8, 32), 512, 0, stream>>>(
      (const __bf16*)ctxb, (const __bf16*)WoT, out, bo, x, MR, Dm, Dm);

  ln_bf16_kernel<<<MR, 256, 0, stream>>>(out, a2, s2, h2);

  // FFN1: M=N=4096 -> 256 tiles, grid (8,32); writes g over dead qkvb/ctxb
  gemm256<2><<<dim3(8, 32, 1), 512, 0, stream>>>(
      (const __bf16*)h2, (const __bf16*)W1T, g, b1, nullptr, MR, FF, Dm, Dm);

  // w2: M=4096,N=1024, split-K=4 (Ks=1024 = 16 K-tiles each), 64 tiles/slice
  // -> 256 blocks = exactly 1/CU. Materialized fp32 partials + reduce
  // (atomic epilogue measured 2.4x worse; 128^2 no-split measured 77us;
  // per-phase pacing barriers measured +2-3us/dispatch worse).
  gemm256<4><<<dim3(8, 8, 4), 512, 0, stream>>>(
      (const __bf16*)g, (const __bf16*)W2T, Pbuf, nullptr, P3buf,
      MR, Dm, FF, FF / 4);
  reduce4_kernel<<<(MR * Dm / 4) / 256, 256, 0, stream>>>(Pbuf, P3buf, b2, out);
}

// Round 13
// 318.335 us; speedup vs baseline: 1.0420x; 1.0420x over previous
//
#include <hip/hip_runtime.h>
#include <hip/hip_bf16.h>

typedef __bf16 bf16x8 __attribute__((ext_vector_type(8)));
typedef float floatx4 __attribute__((ext_vector_type(4)));

constexpr int Dm = 1024;
constexpr int Hh = 16;
constexpr int HD = 64;
constexpr int FF = 4096;
constexpr int Tt = 2048;
constexpr int Bb = 2;
constexpr int MR = Bb * Tt;  // 4096 rows

typedef const __attribute__((address_space(1))) void* gas1p;
typedef __attribute__((address_space(3))) void* las3p;

// ------ fused prep: 6 weight transposes + LN1, one launch ------
__global__ __launch_bounds__(256) void prep_kernel(
    const float* __restrict__ wq, const float* __restrict__ wk,
    const float* __restrict__ wv, const float* __restrict__ wo,
    const float* __restrict__ w1, const float* __restrict__ w2,
    __hip_bfloat16* __restrict__ WqkvT, __hip_bfloat16* __restrict__ WoT,
    __hip_bfloat16* __restrict__ W1T, __hip_bfloat16* __restrict__ W2T,
    const float* __restrict__ x, const float* __restrict__ alpha,
    const float* __restrict__ shift, __hip_bfloat16* __restrict__ h1) {
  int id = blockIdx.x;
  int tid = threadIdx.x;
  if (id < 12288) {
    __shared__ float tile[32][33];
    const float* W;
    __hip_bfloat16* WT;
    int l, sh, K, N;
    if (id < 4096) {
      int m = id >> 10;
      l = id & 1023; sh = 5; K = Dm; N = Dm;
      W = (m == 0) ? wq : (m == 1) ? wk : (m == 2) ? wv : wo;
      WT = (m == 0) ? WqkvT
                    : (m == 1) ? (WqkvT + (size_t)Dm * Dm)
                               : (m == 2) ? (WqkvT + 2 * (size_t)Dm * Dm) : WoT;
    } else if (id < 8192) {
      l = id - 4096; sh = 7; K = Dm; N = FF; W = w1; WT = W1T;
    } else {
      l = id - 8192; sh = 5; K = FF; N = Dm; W = w2; WT = W2T;
    }
    int n0 = (l & ((1 << sh) - 1)) * 32;
    int k0 = (l >> sh) * 32;
    int tx = tid & 31, ty = tid >> 5;
#pragma unroll
    for (int i = 0; i < 4; ++i) {
      int k = k0 + ty + i * 8;
      tile[ty + i * 8][tx] = W[(size_t)k * N + n0 + tx];
    }
    __syncthreads();
    int r = tid >> 3;
    int cq = (tid & 7) * 4;
    __hip_bfloat16 ov[4];
#pragma unroll
    for (int j = 0; j < 4; ++j) ov[j] = __float2bfloat16(tile[cq + j][r]);
    *reinterpret_cast<uint2*>(&WT[(size_t)(n0 + r) * K + k0 + cq]) =
        *reinterpret_cast<const uint2*>(ov);
  } else {
    int row = id - 12288;
    const float4 v = ((const float4*)(x + (size_t)row * Dm))[tid];
    float s = v.x + v.y + v.z + v.w;
    float ss = v.x * v.x + v.y * v.y + v.z * v.z + v.w * v.w;
#pragma unroll
    for (int o = 32; o; o >>= 1) {
      s += __shfl_down(s, o);
      ss += __shfl_down(ss, o);
    }
    __shared__ float rs[4], rss[4];
    int w = tid >> 6, lane = tid & 63;
    if (lane == 0) { rs[w] = s; rss[w] = ss; }
    __syncthreads();
    float tot = rs[0] + rs[1] + rs[2] + rs[3];
    float tots = rss[0] + rss[1] + rss[2] + rss[3];
    float mean = tot * (1.f / Dm);
    float var = tots * (1.f / Dm) - mean * mean;
    float rstd = rsqrtf(var + 1e-5f);
    float4 al = ((const float4*)alpha)[tid];
    float4 sf = ((const float4*)shift)[tid];
    __hip_bfloat16 ov[4];
    ov[0] = __float2bfloat16((v.x - mean) * rstd * al.x + sf.x);
    ov[1] = __float2bfloat16((v.y - mean) * rstd * al.y + sf.y);
    ov[2] = __float2bfloat16((v.z - mean) * rstd * al.z + sf.z);
    ov[3] = __float2bfloat16((v.w - mean) * rstd * al.w + sf.w);
    *reinterpret_cast<uint2*>(h1 + (size_t)row * Dm + tid * 4) =
        *reinterpret_cast<const uint2*>(ov);
  }
}

// ---------------- LayerNorm (fp32 in, bf16 out) ----------------
__global__ __launch_bounds__(256) void ln_bf16_kernel(
    const float* __restrict__ x, const float* __restrict__ alpha,
    const float* __restrict__ shift, __hip_bfloat16* __restrict__ out) {
  int row = blockIdx.x;
  const float4 v = ((const float4*)(x + (size_t)row * Dm))[threadIdx.x];
  float s = v.x + v.y + v.z + v.w;
  float ss = v.x * v.x + v.y * v.y + v.z * v.z + v.w * v.w;
#pragma unroll
  for (int o = 32; o; o >>= 1) {
    s += __shfl_down(s, o);
    ss += __shfl_down(ss, o);
  }
  __shared__ float rs[4], rss[4];
  int w = threadIdx.x >> 6, lane = threadIdx.x & 63;
  if (lane == 0) { rs[w] = s; rss[w] = ss; }
  __syncthreads();
  float tot = rs[0] + rs[1] + rs[2] + rs[3];
  float tots = rss[0] + rss[1] + rss[2] + rss[3];
  float mean = tot * (1.f / Dm);
  float var = tots * (1.f / Dm) - mean * mean;
  float rstd = rsqrtf(var + 1e-5f);
  float4 al = ((const float4*)alpha)[threadIdx.x];
  float4 sf = ((const float4*)shift)[threadIdx.x];
  __hip_bfloat16 ov[4];
  ov[0] = __float2bfloat16((v.x - mean) * rstd * al.x + sf.x);
  ov[1] = __float2bfloat16((v.y - mean) * rstd * al.y + sf.y);
  ov[2] = __float2bfloat16((v.z - mean) * rstd * al.z + sf.z);
  ov[3] = __float2bfloat16((v.w - mean) * rstd * al.w + sf.w);
  *reinterpret_cast<uint2*>(out + (size_t)row * Dm + threadIdx.x * 4) =
      *reinterpret_cast<const uint2*>(ov);
}

// ====== 256x128 GEMM, BK=32, 3 LDS buffers (72KB) -> 2 blocks/CU ==========
// ROUND-13 EXPERIMENT: occupancy at constant burst density. Same proven
// free-slip schedule (reads -> stage -> setprio MFMA burst -> counted
// vmcnt+barrier), same 16-MFMA bursts, but 72KB LDS lets 2 blocks (16 waves)
// co-reside per CU so one block's barrier convoy hides under the other's
// compute. 512 thr / 8 waves (2M x 4N), per-wave 128x32 (acc[8][2]).
// Per K-step(32): 10 ds_read_b128, 3 global_load_lds (A 2 + B 1) for step
// t+2 (depth-2 over 3 buffers), 16 MFMA/wave, ONE vmcnt(3)+barrier.
// Bookkeeping: at end of step t outstanding = {t+1's 3 (issued at t-1)} +
// {t+2's 3 (issued now)}; vmcnt(3) retires t+1's -> ready for next step.
// __launch_bounds__(512,4): 4 waves/EU = 16 waves/CU, caps VGPR at 128.
// EPI 2: +bias, GELU, bf16. EPI 3: QKV scatter, V third transposed to P3.
// EPI 4: split-K fp32 partial (z<3 -> Cout + z*M*N, z==3 -> P3).
// Grid (8, nwg/8, S): bx = XCD owns a contiguous m-band of tiles.
template <int EPI>
__global__ __launch_bounds__(512, 4) void gemmW(
    const __bf16* __restrict__ A, const __bf16* __restrict__ BT,
    void* __restrict__ Cout, const float* __restrict__ bias,
    float* __restrict__ P3, int M, int N, int K, int Ks) {
  __shared__ __bf16 As[3][256 * 32];
  __shared__ __bf16 Bs[3][128 * 32];
  const int tid = threadIdx.x;
  const int w = tid >> 6, lane = tid & 63;
  const int r16 = lane & 15, quad = lane >> 4;
  const int wm = w >> 2, wn = w & 3;  // 2 x 4 wave grid
  const int ntn = N >> 7;
  const int T = blockIdx.x * gridDim.y + blockIdx.y;
  const int tm = T / ntn, tn = T - tm * ntn;
  const int m0 = tm * 256, n0 = tn * 128;
  const int k_off = blockIdx.z * Ks;
  int kcols = K - k_off;
  if (kcols > Ks) kcols = Ks;
  const int nt = kcols >> 5;  // K-steps of 32 (>= 2 at all call sites)
  const __bf16* Ap = A + k_off;
  const __bf16* Bp = BT + k_off;

  // A plane: 256 rows x 32 cols = 16KB = 1024 x 16B chunks -> 2 loads/thread
  // B plane: 128 rows x 32 cols = 8KB  =  512 x 16B chunks -> 1 load/thread
  auto stageA = [&](int t, int buf) {
#pragma unroll
    for (int q = 0; q < 2; ++q) {
      int idx = tid + q * 512;
      int row = idx >> 2;
      int gcb = (idx & 3) ^ ((row >> 1) & 3);
      __builtin_amdgcn_global_load_lds(
          (gas1p)(Ap + (size_t)(m0 + row) * K + t * 32 + gcb * 8),
          (las3p)(&As[buf][idx * 8]), 16, 0, 0);
    }
  };
  auto stageB = [&](int t, int buf) {
    int row = tid >> 2;
    int gcb = (tid & 3) ^ ((row >> 1) & 3);
    __builtin_amdgcn_global_load_lds(
        (gas1p)(Bp + (size_t)(n0 + row) * K + t * 32 + gcb * 8),
        (las3p)(&Bs[buf][tid * 8]), 16, 0, 0);
  };

  int aoffL[8], boffL[2];
#pragma unroll
  for (int i = 0; i < 8; ++i) {
    int ra = wm * 128 + i * 16 + r16;
    aoffL[i] = ra * 32 + (quad ^ ((ra >> 1) & 3)) * 8;
  }
#pragma unroll
  for (int i = 0; i < 2; ++i) {
    int rb = wn * 32 + i * 16 + r16;
    boffL[i] = rb * 32 + (quad ^ ((rb >> 1) & 3)) * 8;
  }

#define LDA(i_) *reinterpret_cast<const bf16x8*>(&As[cur][aoffL[i_]])
#define LDB(i_) *reinterpret_cast<const bf16x8*>(&Bs[cur][boffL[i_]])

  floatx4 acc[8][2] = {};
  stageA(0, 0);
  stageB(0, 0);
  stageA(1, 1);
  stageB(1, 1);
  asm volatile("s_waitcnt vmcnt(3)\n\ts_barrier" ::: "memory");  // tile0 done

  int cur = 0;
  for (int t = 0; t < nt; ++t) {
    bf16x8 b0 = LDB(0), b1 = LDB(1);
    bf16x8 a0 = LDA(0), a1 = LDA(1), a2 = LDA(2), a3 = LDA(3);
    bf16x8 a4 = LDA(4), a5 = LDA(5), a6 = LDA(6), a7 = LDA(7);
    if (t + 2 < nt) {
      int nb = cur + 2;
      if (nb >= 3) nb -= 3;
      stageA(t + 2, nb);
      stageB(t + 2, nb);
    }
    __builtin_amdgcn_s_setprio(1);
    acc[0][0] = __builtin_amdgcn_mfma_f32_16x16x32_bf16(a0, b0, acc[0][0], 0, 0, 0);
    acc[0][1] = __builtin_amdgcn_mfma_f32_16x16x32_bf16(a0, b1, acc[0][1], 0, 0, 0);
    acc[1][0] = __builtin_amdgcn_mfma_f32_16x16x32_bf16(a1, b0, acc[1][0], 0, 0, 0);
    acc[1][1] = __builtin_amdgcn_mfma_f32_16x16x32_bf16(a1, b1, acc[1][1], 0, 0, 0);
    acc[2][0] = __builtin_amdgcn_mfma_f32_16x16x32_bf16(a2, b0, acc[2][0], 0, 0, 0);
    acc[2][1] = __builtin_amdgcn_mfma_f32_16x16x32_bf16(a2, b1, acc[2][1], 0, 0, 0);
    acc[3][0] = __builtin_amdgcn_mfma_f32_16x16x32_bf16(a3, b0, acc[3][0], 0, 0, 0);
    acc[3][1] = __builtin_amdgcn_mfma_f32_16x16x32_bf16(a3, b1, acc[3][1], 0, 0, 0);
    acc[4][0] = __builtin_amdgcn_mfma_f32_16x16x32_bf16(a4, b0, acc[4][0], 0, 0, 0);
    acc[4][1] = __builtin_amdgcn_mfma_f32_16x16x32_bf16(a4, b1, acc[4][1], 0, 0, 0);
    acc[5][0] = __builtin_amdgcn_mfma_f32_16x16x32_bf16(a5, b0, acc[5][0], 0, 0, 0);
    acc[5][1] = __builtin_amdgcn_mfma_f32_16x16x32_bf16(a5, b1, acc[5][1], 0, 0, 0);
    acc[6][0] = __builtin_amdgcn_mfma_f32_16x16x32_bf16(a6, b0, acc[6][0], 0, 0, 0);
    acc[6][1] = __builtin_amdgcn_mfma_f32_16x16x32_bf16(a6, b1, acc[6][1], 0, 0, 0);
    acc[7][0] = __builtin_amdgcn_mfma_f32_16x16x32_bf16(a7, b0, acc[7][0], 0, 0, 0);
    acc[7][1] = __builtin_amdgcn_mfma_f32_16x16x32_bf16(a7, b1, acc[7][1], 0, 0, 0);
    __builtin_amdgcn_s_setprio(0);
    if (t + 1 < nt)
      asm volatile("s_waitcnt vmcnt(3)\n\ts_barrier" ::: "memory");
    else
      asm volatile("s_waitcnt vmcnt(0)\n\ts_barrier" ::: "memory");
    cur = (cur == 2) ? 0 : cur + 1;
  }
#undef LDA
#undef LDB

  if (EPI == 3) {
    // fused QKV scatter; V third (qkv==2) written transposed into vtb (=P3)
    __hip_bfloat16* qk = (__hip_bfloat16*)Cout;
    __hip_bfloat16* vtb = (__hip_bfloat16*)P3;
#pragma unroll
    for (int mi = 0; mi < 8; ++mi)
#pragma unroll
      for (int ni = 0; ni < 2; ++ni) {
        int row0 = m0 + wm * 128 + mi * 16 + quad * 4;
        int col = n0 + wn * 32 + ni * 16 + r16;
        int qkv = col >> 10, rem = col & 1023;
        int h = rem >> 6, d = rem & 63;
        int bb = row0 >> 11, t0 = row0 & 2047;
        if (qkv < 2) {
#pragma unroll
          for (int r = 0; r < 4; ++r)
            qk[(size_t)qkv * (MR * Dm) +
               ((size_t)(bb * Hh + h) * Tt + t0 + r) * HD + d] =
                __float2bfloat16(acc[mi][ni][r]);
        } else {
          __hip_bfloat16 ov[4];
#pragma unroll
          for (int r = 0; r < 4; ++r) ov[r] = __float2bfloat16(acc[mi][ni][r]);
          *reinterpret_cast<uint2*>(
              &vtb[((size_t)(bb * Hh + h) * HD + d) * Tt + t0]) =
              *reinterpret_cast<const uint2*>(ov);
        }
      }
    return;
  }

  float* dst4 = nullptr;
  if (EPI == 4)
    dst4 = (blockIdx.z == 3) ? P3
                             : (float*)Cout + (size_t)blockIdx.z * ((size_t)M * N);
#pragma unroll
  for (int mi = 0; mi < 8; ++mi)
#pragma unroll
    for (int ni = 0; ni < 2; ++ni)
#pragma unroll
      for (int r = 0; r < 4; ++r) {
        int row = m0 + wm * 128 + mi * 16 + quad * 4 + r;
        int col = n0 + wn * 32 + ni * 16 + r16;
        float vacc = acc[mi][ni][r];
        if (EPI == 2) {
          vacc += bias[col];
          float u = vacc + 0.044715f * vacc * vacc * vacc;
          float e = __builtin_amdgcn_exp2f(2.3025851f * u);
          float th = 1.f - 2.f * __builtin_amdgcn_rcpf(e + 1.f);
          ((__hip_bfloat16*)Cout)[(size_t)row * N + col] =
              __float2bfloat16(0.5f * vacc * (1.f + th));
        } else {  // EPI 4: split-K raw partial, fp32
          dst4[(size_t)row * N + col] = vacc;
        }
      }
}

// ---- split-K=4 reduce: out = P0+P1+P2+P3 + bias + out (out holds x2) ----
__global__ __launch_bounds__(256) void reduce4_kernel(
    const float* __restrict__ P, const float* __restrict__ P3,
    const float* __restrict__ bias, float* __restrict__ out) {
  size_t idx = (size_t)blockIdx.x * 256 + threadIdx.x;  // float4 index
  const size_t MN4 = (size_t)MR * Dm / 4;
  float4 p0 = ((const float4*)P)[idx];
  float4 p1 = ((const float4*)P)[MN4 + idx];
  float4 p2 = ((const float4*)P)[2 * MN4 + idx];
  float4 p3 = ((const float4*)P3)[idx];
  float4 b = ((const float4*)bias)[idx & (Dm / 4 - 1)];
  float4 o = ((float4*)out)[idx];
  o.x += p0.x + p1.x + p2.x + p3.x + b.x;
  o.y += p0.y + p1.y + p2.y + p3.y + b.y;
  o.z += p0.z + p1.z + p2.z + p3.z + b.z;
  o.w += p0.w + p1.w + p2.w + p3.w + b.w;
  ((float4*)out)[idx] = o;
}

// ============ 128x128 GEMM, 4-phase thinned schedule (wo ONLY) =============
__global__ __launch_bounds__(512, 4) void gemm128(
    const __bf16* __restrict__ A, const __bf16* __restrict__ BT,
    float* __restrict__ Cout, const float* __restrict__ bias,
    const float* __restrict__ resid, int M, int N, int K) {
  __shared__ __bf16 As[2][2][128 * 32];
  __shared__ __bf16 Bs[2][2][128 * 32];
  const int tid = threadIdx.x;
  const int w = tid >> 6, lane = tid & 63;
  const int r16 = lane & 15, quad = lane >> 4;
  const int wm = w >> 2, wn = w & 3;  // 2 x 4 wave grid
  const int ntn = N >> 7;
  const int T = blockIdx.x * gridDim.y + blockIdx.y;
  const int tm = T / ntn, tn = T - tm * ntn;
  const int m0 = tm * 128, n0 = tn * 128;
  const int nt = K >> 6;

  const int s_row = tid >> 2;
  const int s_gcb = (tid & 3) ^ ((s_row >> 1) & 3);
  auto stageA = [&](int t, int pl, int buf) {
    __builtin_amdgcn_global_load_lds(
        (gas1p)(A + (size_t)(m0 + s_row) * K + t * 64 + pl * 32 + s_gcb * 8),
        (las3p)(&As[buf][pl][tid * 8]), 16, 0, 0);
  };
  auto stageB = [&](int t, int pl, int buf) {
    __builtin_amdgcn_global_load_lds(
        (gas1p)(BT + (size_t)(n0 + s_row) * K + t * 64 + pl * 32 + s_gcb * 8),
        (las3p)(&Bs[buf][pl][tid * 8]), 16, 0, 0);
  };

  int aoffL[4], boffL[2];
#pragma unroll
  for (int i = 0; i < 4; ++i) {
    int ra = wm * 64 + i * 16 + r16;
    aoffL[i] = ra * 32 + (quad ^ ((ra >> 1) & 3)) * 8;
  }
#pragma unroll
  for (int i = 0; i < 2; ++i) {
    int rb = wn * 32 + i * 16 + r16;
    boffL[i] = rb * 32 + (quad ^ ((rb >> 1) & 3)) * 8;
  }

#define LDA(pl_, i_) *reinterpret_cast<const bf16x8*>(&As[c][pl_][aoffL[i_]])
#define LDB(pl_, i_) *reinterpret_cast<const bf16x8*>(&Bs[c][pl_][boffL[i_]])
#define MFMA2(acc_, a_)                                                        \
  acc_[0] = __builtin_amdgcn_mfma_f32_16x16x32_bf16(a_, b0, acc_[0], 0, 0, 0); \
  acc_[1] = __builtin_amdgcn_mfma_f32_16x16x32_bf16(a_, b1, acc_[1], 0, 0, 0);

  floatx4 acc[4][2] = {};
  stageA(0, 0, 0);
  stageB(0, 0, 0);
  stageA(0, 1, 0);
  stageB(0, 1, 0);
  asm volatile("s_waitcnt vmcnt(2)\n\ts_barrier" ::: "memory");

  for (int t = 0; t < nt; ++t) {
    const int c = t & 1, nc = c ^ 1;
    const bool pre = (t + 1 < nt);
    bf16x8 a0, a1, b0, b1;
    b0 = LDB(0, 0); b1 = LDB(0, 1);
    a0 = LDA(0, 0); a1 = LDA(0, 1);
    if (pre) stageA(t + 1, 0, nc);
    __builtin_amdgcn_s_setprio(1);
    MFMA2(acc[0], a0); MFMA2(acc[1], a1);
    __builtin_amdgcn_s_setprio(0);
    a0 = LDA(0, 2); a1 = LDA(0, 3);
    if (pre) stageB(t + 1, 0, nc);
    __builtin_amdgcn_s_setprio(1);
    MFMA2(acc[2], a0); MFMA2(acc[3], a1);
    __builtin_amdgcn_s_setprio(0);
    if (pre)
      asm volatile("s_waitcnt vmcnt(2)\n\ts_barrier" ::: "memory");
    else
      asm volatile("s_waitcnt vmcnt(0)\n\ts_barrier" ::: "memory");
    b0 = LDB(1, 0); b1 = LDB(1, 1);
    a0 = LDA(1, 0); a1 = LDA(1, 1);
    if (pre) stageA(t + 1, 1, nc);
    __builtin_amdgcn_s_setprio(1);
    MFMA2(acc[0], a0); MFMA2(acc[1], a1);
    __builtin_amdgcn_s_setprio(0);
    a0 = LDA(1, 2); a1 = LDA(1, 3);
    if (pre) stageB(t + 1, 1, nc);
    __builtin_amdgcn_s_setprio(1);
    MFMA2(acc[2], a0); MFMA2(acc[3], a1);
    __builtin_amdgcn_s_setprio(0);
    if (pre)
      asm volatile("s_waitcnt vmcnt(2)\n\ts_barrier" ::: "memory");
    else
      asm volatile("s_waitcnt vmcnt(0)\n\ts_barrier" ::: "memory");
  }
#undef LDA
#undef LDB
#undef MFMA2

#pragma unroll
  for (int mi = 0; mi < 4; ++mi)
#pragma unroll
    for (int ni = 0; ni < 2; ++ni)
#pragma unroll
      for (int r = 0; r < 4; ++r) {
        int row = m0 + wm * 64 + mi * 16 + quad * 4 + r;
        int col = n0 + wn * 32 + ni * 16 + r16;
        float vacc = acc[mi][ni][r] + bias[col] + resid[(size_t)row * N + col];
        Cout[(size_t)row * N + col] = vacc;
      }
}

// ---------------- MFMA flash attention, fixed-max softmax ----------------
__global__ __launch_bounds__(256) void attn_kernel(
    const __bf16* __restrict__ qp, const __bf16* __restrict__ kp,
    const __bf16* __restrict__ vtp, __bf16* __restrict__ ctx) {
  __shared__ __bf16 Ks[2][64 * 64];   // [kcol][d], swizzled chunks
  __shared__ __bf16 Vt[2][80 * 64];   // [d][kcol]; rows 64..79: ones/zeros
  __shared__ __bf16 Ps[4 * 16 * 72];  // per-wave P [qrow][kcol]
  int bh = blockIdx.x;
  int b = bh >> 4, h = bh & 15;
  int qt = 31 - blockIdx.y;  // longest blocks first
  int tid = threadIdx.x;
  int w = tid >> 6, lane = tid & 63;
  int r16 = lane & 15, quad = lane >> 4;
  int q0 = qt * 64;
  const size_t base = (size_t)bh * Tt * HD;

  {
    int r = 64 + (tid >> 4);
    int c = (tid & 15) * 4;
    __bf16 val = (r == 64) ? (__bf16)1.0f : (__bf16)0.0f;
#pragma unroll
    for (int bu = 0; bu < 2; ++bu) {
      __bf16* p = &Vt[bu][r * 64 + c];
      p[0] = val; p[1] = val; p[2] = val; p[3] = val;
    }
  }

  const float QS = 0.125f * 1.44269504088896f;
  bf16x8 aq[2];
#pragma unroll
  for (int ks = 0; ks < 2; ++ks) {
    bf16x8 t = *reinterpret_cast<const bf16x8*>(
        qp + base + (size_t)(q0 + w * 16 + r16) * HD + ks * 32 + quad * 8);
#pragma unroll
    for (int j = 0; j < 8; ++j) t[j] = (__bf16)((float)t[j] * QS);
    aq[ks] = t;
  }

  auto stage = [&](int kt, int buf) {
#pragma unroll
    for (int p = 0; p < 2; ++p) {
      int idx = tid + p * 256;
      int row = idx >> 3, c = idx & 7;
      int gc = c ^ (row & 7);
      __builtin_amdgcn_global_load_lds(
          (gas1p)(kp + base + (size_t)(kt * 64 + row) * HD + gc * 8),
          (las3p)(&Ks[buf][idx * 8]), 16, 0, 0);
      __builtin_amdgcn_global_load_lds(
          (gas1p)(vtp + base + (size_t)row * Tt + kt * 64 + gc * 8),
          (las3p)(&Vt[buf][idx * 8]), 16, 0, 0);
    }
  };

  floatx4 O[5] = {};
  stage(0, 0);
  for (int kt = 0; kt <= qt; ++kt) {
    int cur = kt & 1;
    __syncthreads();
    if (kt < qt) stage(kt + 1, cur ^ 1);

    floatx4 sacc[4] = {};
#pragma unroll
    for (int ks = 0; ks < 2; ++ks)
#pragma unroll
      for (int ni = 0; ni < 4; ++ni) {
        int row = ni * 16 + r16;
        bf16x8 bk = *reinterpret_cast<const bf16x8*>(
            &Ks[cur][row * 64 + (((ks << 2) | quad) ^ (r16 & 7)) * 8]);
        sacc[ni] = __builtin_amdgcn_mfma_f32_16x16x32_bf16(aq[ks], bk, sacc[ni], 0, 0, 0);
      }

    bool diag = (kt == qt);
#pragma unroll
    for (int ni = 0; ni < 4; ++ni)
#pragma unroll
      for (int r = 0; r < 4; ++r) {
        float sv = sacc[ni][r];
        if (diag)
          sv = (ni * 16 + r16 <= w * 16 + quad * 4 + r) ? sv : -__builtin_inff();
        Ps[w * 1152 + (quad * 4 + r) * 72 + ni * 16 + r16] =
            (__bf16)__builtin_amdgcn_exp2f(sv);
      }

#pragma unroll
    for (int ks = 0; ks < 2; ++ks) {
      bf16x8 ap = *reinterpret_cast<const bf16x8*>(
          &Ps[w * 1152 + r16 * 72 + ks * 32 + quad * 8]);
#pragma unroll
      for (int ni = 0; ni < 5; ++ni) {
        int row = ni * 16 + r16;
        bf16x8 bv = *reinterpret_cast<const bf16x8*>(
            &Vt[cur][row * 64 + (((ks << 2) | quad) ^ (r16 & 7)) * 8]);
        O[ni] = __builtin_amdgcn_mfma_f32_16x16x32_bf16(ap, bv, O[ni], 0, 0, 0);
      }
    }
  }

  float invl[4];
#pragma unroll
  for (int r = 0; r < 4; ++r) {
    float l = __shfl(O[4][r], lane & 48);
    invl[r] = 1.f / l;
  }
#pragma unroll
  for (int r = 0; r < 4; ++r) {
    int qrow = q0 + w * 16 + quad * 4 + r;
    __bf16* op = ctx + ((size_t)(b * Tt + qrow)) * Dm + h * HD;
#pragma unroll
    for (int ni = 0; ni < 4; ++ni)
      op[ni * 16 + r16] = (__bf16)(O[ni][r] * invl[r]);
  }
}

extern "C" void kernel_launch(void* const* d_in, const int* in_sizes, int n_in,
                              void* d_out, int out_size, void* d_ws, size_t ws_size,
                              hipStream_t stream) {
  const float* x = (const float*)d_in[0];
  const float* wq = (const float*)d_in[1];
  const float* wk = (const float*)d_in[2];
  const float* wv = (const float*)d_in[3];
  const float* wo = (const float*)d_in[4];
  const float* bo = (const float*)d_in[5];
  const float* w1 = (const float*)d_in[6];
  const float* b1 = (const float*)d_in[7];
  const float* w2 = (const float*)d_in[8];
  const float* b2 = (const float*)d_in[9];
  const float* a1 = (const float*)d_in[10];
  const float* s1 = (const float*)d_in[11];
  const float* a2 = (const float*)d_in[12];
  const float* s2 = (const float*)d_in[13];
  float* out = (float*)d_out;
  char* ws = (char*)d_ws;

  const size_t MB = 1024 * 1024;
  __hip_bfloat16* WqkvT = (__hip_bfloat16*)(ws + 0 * MB);  // 6MB: WqT|WkT|WvT
  __hip_bfloat16* WoT = (__hip_bfloat16*)(ws + 6 * MB);
  __hip_bfloat16* W1T = (__hip_bfloat16*)(ws + 8 * MB);
  __hip_bfloat16* W2T = (__hip_bfloat16*)(ws + 16 * MB);
  __hip_bfloat16* h1  = (__hip_bfloat16*)(ws + 24 * MB);
  __hip_bfloat16* qkvb = (__hip_bfloat16*)(ws + 32 * MB);  // 16MB used: q|k head-major
  __hip_bfloat16* ctxb = (__hip_bfloat16*)(ws + 56 * MB);  // token-major
  __hip_bfloat16* h2  = (__hip_bfloat16*)(ws + 64 * MB);
  // g (FFN1 out, 32MB) overlays dead qkvb+ctxb at [32,64).
  __hip_bfloat16* g   = (__hip_bfloat16*)(ws + 32 * MB);
  __hip_bfloat16* vtb = (__hip_bfloat16*)(ws + 104 * MB);  // 8MB: V^T [B*H,64,T]
  // split-K=4 fp32 partials: slices 0-2 (48MB) at [64,112) over dead h2/vtb;
  // slice 3 (16MB) at [0,16) over dead WqkvT/WoT/W1T (all consumed by w2 time)
  float* Pbuf = (float*)(ws + 64 * MB);
  float* P3buf = (float*)(ws + 0 * MB);

  // one launch: 6 weight transposes + LN1 (disjoint block ranges)
  prep_kernel<<<12288 + MR, 256, 0, stream>>>(
      wq, wk, wv, wo, w1, w2, WqkvT, WoT, W1T, W2T, x, a1, s1, h1);

  // QKV: tiles 16 x 24 = 384 blocks (1.5/CU). V third -> vtb transposed.
  gemmW<3><<<dim3(8, 48, 1), 512, 0, stream>>>(
      (const __bf16*)h1, (const __bf16*)WqkvT, qkvb, nullptr, (float*)vtb,
      MR, 3 * Dm, Dm, Dm);

  attn_kernel<<<dim3(Bb * Hh, Tt / 64), 256, 0, stream>>>(
      (const __bf16*)qkvb, (const __bf16*)(qkvb + (size_t)MR * Dm),
      (const __bf16*)vtb, (__bf16*)ctxb);

  // x2 = ctx @ Wo + bo + x
  gemm128<<<dim3(8, 32), 512, 0, stream>>>(
      (const __bf16*)ctxb, (const __bf16*)WoT, out, bo, x, MR, Dm, Dm);

  ln_bf16_kernel<<<MR, 256, 0, stream>>>(out, a2, s2, h2);

  // FFN1: tiles 16 x 32 = 512 blocks (2/CU)
  gemmW<2><<<dim3(8, 64, 1), 512, 0, stream>>>(
      (const __bf16*)h2, (const __bf16*)W1T, g, b1, nullptr, MR, FF, Dm, Dm);

  // w2: tiles 16 x 8 = 128 per slice, split-K=4 -> 512 blocks (2/CU)
  gemmW<4><<<dim3(8, 16, 4), 512, 0, stream>>>(
      (const __bf16*)g, (const __bf16*)W2T, Pbuf, nullptr, P3buf,
      MR, Dm, FF, FF / 4);
  reduce4_kernel<<<(MR * Dm / 4) / 256, 256, 0, stream>>>(Pbuf, P3buf, b2, out);
}